// Round 4
// baseline (114.549 us; speedup 1.0000x reference)
//
#include <hip/hip_runtime.h>

typedef float vf4 __attribute__((ext_vector_type(4)));
typedef float vf2 __attribute__((ext_vector_type(2)));

#define LOG2E 1.4426950408889634f
#define TWO_LOG2E 2.8853900817779268f

__device__ __forceinline__ float fexp2(float x) { return __builtin_amdgcn_exp2f(x); }
__device__ __forceinline__ float frcp(float x) { return __builtin_amdgcn_rcpf(x); }

// ---------------------------------------------------------------------------
// Kernel 1: projections, k-split x2, exp folded into the epilogue (stores
// Ep = exp2(2*log2e * acc_half); scores uses tanh(q+k) = 1 - 2/(Eq*Fk+1)).
// v2 (this round): 128-thread blocks, 8m x 4n per-thread micro-tile
// (3 b128 LDS reads per 32 FMA vs 2 per 16 before), W panel staged ONCE
// per block (transposed [k][n], 34.8 KB), A tiles register-double-buffered
// with one __syncthreads per 16-k step. Grid 64x4x2 = 512 = 2 blocks/CU.
__global__ __launch_bounds__(128) void proj_kernel(
    const float* __restrict__ queries, const float* __restrict__ keyes,
    const float* __restrict__ Wq, const float* __restrict__ Wk,
    float* __restrict__ QpH, float* __restrict__ KpH,
    float* __restrict__ Rsum) {
  __shared__ alignas(16) float Bs[128 * 68];    // [k][n] W panel (whole k-half)
  __shared__ alignas(16) float At[2][16 * 68];  // [k][m] double-buffered
  const int t = threadIdx.x;
  if (blockIdx.x == 0 && blockIdx.y == 0 && blockIdx.z == 0) {
#pragma unroll
    for (int c = 0; c < 4; ++c)
      *(vf4*)&Rsum[t * 16 + c * 4] = (vf4){0.f, 0.f, 0.f, 0.f};
  }
  const int m0 = blockIdx.x * 64;
  const int n0 = blockIdx.y * 64;
  const int k0 = blockIdx.z * 128;  // k-half
  const bool isQ = (m0 < 2048);
  const float* X = isQ ? queries : keyes;
  const float* W = isQ ? Wq : Wk;
  float* C = (isQ ? QpH : KpH) + blockIdx.z * 524288;
  const int mb = isQ ? m0 : (m0 - 2048);

  // ---- stage W panel once: Bs[k][n], k = 0..127 (rel), n = 0..63 ----
  {
    const int wn = t & 63;
    const int wh = t >> 6;  // 0..1 -> k-range half
    const float* wsrc = &W[(n0 + wn) * 256 + k0 + wh * 64];
#pragma unroll
    for (int c4 = 0; c4 < 64; c4 += 4) {
      vf4 wv = *(const vf4*)&wsrc[c4];
#pragma unroll
      for (int e = 0; e < 4; ++e) Bs[(wh * 64 + c4 + e) * 68 + wn] = wv[e];
    }
  }

  // ---- A staging: lm = row 0..63, lq = k-octet 0..1 (8 floats each) ----
  const int lm = t >> 1;
  const int lq = t & 1;
  vf4 ra0, ra1;  // in-flight A tile (registers)
  {
    const float* src = &X[(mb + lm) * 256 + k0 + lq * 8];
    ra0 = *(const vf4*)src;
    ra1 = *(const vf4*)(src + 4);
#pragma unroll
    for (int c = 0; c < 4; ++c) At[0][(lq * 8 + c) * 68 + lm] = ra0[c];
#pragma unroll
    for (int c = 0; c < 4; ++c) At[0][(lq * 8 + 4 + c) * 68 + lm] = ra1[c];
    src = &X[(mb + lm) * 256 + k0 + 16 + lq * 8];  // prefetch tile 1
    ra0 = *(const vf4*)src;
    ra1 = *(const vf4*)(src + 4);
  }
  __syncthreads();

  const int tm8 = (t & 7) * 8;   // m-octet
  const int tn4 = (t >> 3) * 4;  // n-quad (0..60)

  float acc[8][4] = {};
#pragma unroll
  for (int s = 0; s < 8; ++s) {
    // write tile s+1 (held in regs) into the buffer iteration s-1 finished with
    if (s < 7) {
#pragma unroll
      for (int c = 0; c < 4; ++c) At[(s + 1) & 1][(lq * 8 + c) * 68 + lm] = ra0[c];
#pragma unroll
      for (int c = 0; c < 4; ++c) At[(s + 1) & 1][(lq * 8 + 4 + c) * 68 + lm] = ra1[c];
    }
    if (s < 6) {  // prefetch tile s+2 (latency hides under compute below)
      const float* src = &X[(mb + lm) * 256 + k0 + (s + 2) * 16 + lq * 8];
      ra0 = *(const vf4*)src;
      ra1 = *(const vf4*)(src + 4);
    }
    const float* ab = At[s & 1];
    const float* bb = &Bs[s * 16 * 68];
#pragma unroll
    for (int kk = 0; kk < 16; ++kk) {
      vf4 a0 = *(const vf4*)&ab[kk * 68 + tm8];
      vf4 a1 = *(const vf4*)&ab[kk * 68 + tm8 + 4];
      vf4 b4 = *(const vf4*)&bb[kk * 68 + tn4];
#pragma unroll
      for (int i = 0; i < 4; ++i)
#pragma unroll
        for (int j = 0; j < 4; ++j) {
          acc[i][j] += a0[i] * b4[j];
          acc[i + 4][j] += a1[i] * b4[j];
        }
    }
    if (s < 7) __syncthreads();
  }
#pragma unroll
  for (int i = 0; i < 8; ++i) {
    vf4 o = {fexp2(acc[i][0] * TWO_LOG2E), fexp2(acc[i][1] * TWO_LOG2E),
             fexp2(acc[i][2] * TWO_LOG2E), fexp2(acc[i][3] * TWO_LOG2E)};
    *(vf4*)&C[(mb + tm8 + i) * 256 + n0 + tn4] = o;
  }
}

// ---------------------------------------------------------------------------
// Kernel 2 (dominant): scores via precomputed exponentials.  Unchanged from
// R3 (validated): Wv through scalar cache, 4-way rational rcp combining.
// score = Swv - 2*acc;  E[b][j][i] = masked ? 1 : exp(score); fused row sums
// via atomicAdd into Rsum. Tile 32i x 32j x h=256, grid 8x8x8 = 512.
__global__ __launch_bounds__(256) void scores_exp_kernel(
    const float* __restrict__ QpH, const float* __restrict__ KpH,
    const float* __restrict__ Wv, const int* __restrict__ valid_lens,
    float* __restrict__ E, float* __restrict__ Rsum) {
  __shared__ alignas(16) float Qs[32 * 32];
  __shared__ alignas(16) float Ks[32 * 32];
  const int t = threadIdx.x;
  const int i0 = blockIdx.x * 32;
  const int j0 = blockIdx.y * 32;
  const int b = blockIdx.z;
  const int ti = t & 15;   // i = i0 + ti (+16)
  const int tj = t >> 4;   // j = j0 + tj (+16)

  float Swv;  // sum_h wv[h]
  {
    vf4 w4 = *(const vf4*)&Wv[(t & 63) * 4];
    float sw = w4[0] + w4[1] + w4[2] + w4[3];
#pragma unroll
    for (int off = 1; off < 64; off <<= 1) sw += __shfl_xor(sw, off, 64);
    Swv = sw;
  }

  const int srow = t >> 3;       // staging row 0..31
  const int scg = t & 7;         // staging col-group 0..7
  const int swcol = ((scg ^ (srow & 7)) << 2);
  const int qxor = ti & 7;
  const int kxor = tj & 7;

  float acc[2][2] = {};
  for (int hc = 0; hc < 8; ++hc) {
    __syncthreads();
    const int qoff = (((b << 8) + i0 + srow) << 8) + hc * 32 + scg * 4;
    const int koff = (((b << 8) + j0 + srow) << 8) + hc * 32 + scg * 4;
    vf4 qv = *(const vf4*)&QpH[qoff];
    vf4 qv2 = *(const vf4*)&QpH[524288 + qoff];
    vf4 kv = *(const vf4*)&KpH[koff];
    vf4 kv2 = *(const vf4*)&KpH[524288 + koff];
    *(vf4*)&Qs[srow * 32 + swcol] = qv * qv2;  // product of half-exps
    *(vf4*)&Ks[srow * 32 + swcol] = kv * kv2;
    __syncthreads();
#pragma unroll
    for (int hh = 0; hh < 8; ++hh) {
      vf4 q0 = *(const vf4*)&Qs[ti * 32 + ((hh ^ qxor) << 2)];
      vf4 q1 = *(const vf4*)&Qs[(ti + 16) * 32 + ((hh ^ qxor) << 2)];
      vf4 k0 = *(const vf4*)&Ks[tj * 32 + ((hh ^ kxor) << 2)];
      vf4 k1 = *(const vf4*)&Ks[(tj + 16) * 32 + ((hh ^ kxor) << 2)];
      const int hb = hc * 32 + hh * 4;
      const float w0 = Wv[hb + 0];  // uniform -> scalar cache, not LDS
      const float w1 = Wv[hb + 1];
      const float w2 = Wv[hb + 2];
      const float w3 = Wv[hb + 3];
      // sum_e w_e / A_e with one rcp: (n01*d23 + n23*d01) / (d01*d23)
      auto term = [&](const vf4& q, const vf4& k, float& a) {
        float A0 = __builtin_fmaf(q[0], k[0], 1.0f);
        float A1 = __builtin_fmaf(q[1], k[1], 1.0f);
        float A2 = __builtin_fmaf(q[2], k[2], 1.0f);
        float A3 = __builtin_fmaf(q[3], k[3], 1.0f);
        float d01 = A0 * A1;
        float d23 = A2 * A3;
        float n01 = __builtin_fmaf(w0, A1, w1 * A0);
        float n23 = __builtin_fmaf(w2, A3, w3 * A2);
        float num = __builtin_fmaf(n01, d23, n23 * d01);
        a = __builtin_fmaf(num, frcp(d01 * d23), a);
      };
      term(q0, k0, acc[0][0]);
      term(q0, k1, acc[0][1]);
      term(q1, k0, acc[1][0]);
      term(q1, k1, acc[1][1]);
    }
  }

  const int len = valid_lens[b];
#pragma unroll
  for (int c = 0; c < 2; ++c) {
    const int j = j0 + tj + 16 * c;
    const bool masked = (j >= len);
    float ev[2];
#pragma unroll
    for (int r = 0; r < 2; ++r) {
      const int i = i0 + ti + 16 * r;
      const float score = Swv - 2.0f * acc[r][c];
      ev[r] = masked ? 1.0f : fexp2(score * LOG2E);
      E[(((b << 8) + j) << 8) + i] = ev[r];
    }
    float s = ev[0] + ev[1];
#pragma unroll
    for (int off = 1; off < 16; off <<= 1) s += __shfl_xor(s, off, 64);
    if (ti == 0) atomicAdd(&Rsum[(b << 8) + j], s);
  }
}

// ---------------------------------------------------------------------------
// Kernel 3: out[b,i,d] = sum_j (E[b,j,i]/Rsum[b,j]) * V[b,j,d].
// v2 (this round): i micro-tile is consecutive {2ti, 2ti+1} so the two
// A-reads fuse into one b64 (was two strided b32): 23.6 -> 18 cy/j per wave.
// Tile 32i x 64d, 256 threads, grid 8x4x8 = 256 blocks.
__global__ __launch_bounds__(256) void out_kernel(
    const float* __restrict__ E, const float* __restrict__ Rsum,
    const float* __restrict__ V, float* __restrict__ out) {
  __shared__ alignas(16) float As[32 * 36];  // [j][i]
  __shared__ alignas(16) float Bs[32 * 68];  // [j][d]
  const int t = threadIdx.x;
  const int i0 = blockIdx.x * 32;
  const int d0 = blockIdx.y * 64;
  const int b = blockIdx.z;
  const int ti = t & 15;   // i-pair: rows 2ti, 2ti+1
  const int td = t >> 4;   // d = d0 + td*4
  const int sr = t >> 3;   // staging row 0..31
  const int sc4 = (t & 7) * 4;

  float acc[2][4] = {};
  for (int jc = 0; jc < 8; ++jc) {
    const int jb = jc * 32;
    __syncthreads();
    const float rj = frcp(Rsum[(b << 8) + jb + sr]);
    {
      vf4 a = *(const vf4*)&E[(((b << 8) + jb + sr) << 8) + i0 + sc4];
      *(vf4*)&As[sr * 36 + sc4] = a * rj;
    }
#pragma unroll
    for (int s = 0; s < 2; ++s) {
      const int col = sc4 + s * 32;
      *(vf4*)&Bs[sr * 68 + col] =
          *(const vf4*)&V[(((b << 8) + jb + sr) << 8) + d0 + col];
    }
    __syncthreads();
#pragma unroll
    for (int j = 0; j < 32; ++j) {
      vf2 a = *(const vf2*)&As[j * 36 + 2 * ti];  // rows 2ti, 2ti+1
      vf4 b4 = *(const vf4*)&Bs[j * 68 + td * 4];
#pragma unroll
      for (int c = 0; c < 4; ++c) {
        acc[0][c] += a[0] * b4[c];
        acc[1][c] += a[1] * b4[c];
      }
    }
  }
#pragma unroll
  for (int r = 0; r < 2; ++r) {
    vf4 o = {acc[r][0], acc[r][1], acc[r][2], acc[r][3]};
    *(vf4*)&out[(((b << 8) + i0 + 2 * ti + r) << 8) + d0 + td * 4] = o;
  }
}

// ---------------------------------------------------------------------------
extern "C" void kernel_launch(void* const* d_in, const int* in_sizes, int n_in,
                              void* d_out, int out_size, void* d_ws, size_t ws_size,
                              hipStream_t stream) {
  const float* queries = (const float*)d_in[0];
  const float* keyes = (const float*)d_in[1];
  const float* values = (const float*)d_in[2];
  const int* valid_lens = (const int*)d_in[3];
  const float* Wq = (const float*)d_in[4];
  const float* Wk = (const float*)d_in[5];
  const float* Wv = (const float*)d_in[6];
  float* out = (float*)d_out;

  float* QpH = (float*)d_ws;       // 2 x 2 MB (k-half exponentials)
  float* KpH = QpH + 2 * 524288;   // 2 x 2 MB
  float* E = KpH + 2 * 524288;     // 2 MB, [b][j][i]
  float* Rsum = E + 524288;        // 8 KB, [b][j]

  proj_kernel<<<dim3(64, 4, 2), 128, 0, stream>>>(queries, keyes, Wq, Wk,
                                                  QpH, KpH, Rsum);
  scores_exp_kernel<<<dim3(8, 8, 8), 256, 0, stream>>>(QpH, KpH, Wv,
                                                       valid_lens, E, Rsum);
  out_kernel<<<dim3(8, 4, 8), 256, 0, stream>>>(E, Rsum, values, out);
}

// Round 5
// 106.698 us; speedup vs baseline: 1.0736x; 1.0736x over previous
//
#include <hip/hip_runtime.h>

typedef float vf4 __attribute__((ext_vector_type(4)));
typedef float vf2 __attribute__((ext_vector_type(2)));

#define LOG2E 1.4426950408889634f
#define TWO_LOG2E 2.8853900817779268f

__device__ __forceinline__ float fexp2(float x) { return __builtin_amdgcn_exp2f(x); }
__device__ __forceinline__ float frcp(float x) { return __builtin_amdgcn_rcpf(x); }

// ---------------------------------------------------------------------------
// Kernel 1: projections (R3-proven version: 256 threads, 4x4 micro-tile,
// 8 waves/CU). k-split x2, exp folded into epilogue: stores
// Ep = exp2(2*log2e * acc_half); scores uses tanh(q+k) = 1 - 2/(Eq*Fk+1).
// Rows 0..2047 = queries@Wq^T -> QpH, else keyes@Wk^T -> KpH.
// Block (0,0,0) also zeroes Rsum[2048].
// NOTE (R4 post-mortem): do NOT drop this to 128-thread blocks — grid 512
// at 128 thr = 1 wave/SIMD, kills latency hiding (-7 us measured).
__global__ __launch_bounds__(256) void proj_kernel(
    const float* __restrict__ queries, const float* __restrict__ keyes,
    const float* __restrict__ Wq, const float* __restrict__ Wk,
    float* __restrict__ QpH, float* __restrict__ KpH,
    float* __restrict__ Rsum) {
  __shared__ alignas(16) float At[16 * 68];  // [k][m]
  __shared__ alignas(16) float Bt[16 * 68];  // [k][n]
  const int t = threadIdx.x;
  if (blockIdx.x == 0 && blockIdx.y == 0 && blockIdx.z == 0) {
    *(vf4*)&Rsum[t * 8] = (vf4){0.f, 0.f, 0.f, 0.f};
    *(vf4*)&Rsum[t * 8 + 4] = (vf4){0.f, 0.f, 0.f, 0.f};
  }
  const int m0 = blockIdx.x * 64;
  const int n0 = blockIdx.y * 64;
  const int k0 = blockIdx.z * 128;  // k-half
  const bool isQ = (m0 < 2048);
  const float* X = isQ ? queries : keyes;
  const float* W = isQ ? Wq : Wk;
  float* C = (isQ ? QpH : KpH) + blockIdx.z * 524288;
  const int mb = isQ ? m0 : (m0 - 2048);

  const int lm = t >> 2;
  const int lq = t & 3;
  const int mm4 = (t & 15) * 4;
  const int nn4 = (t >> 4) * 4;

  float acc[4][4] = {};
  for (int kc = k0; kc < k0 + 128; kc += 16) {
    __syncthreads();
    vf4 xa = *(const vf4*)&X[(mb + lm) * 256 + kc + lq * 4];
    vf4 wb = *(const vf4*)&W[(n0 + lm) * 256 + kc + lq * 4];
#pragma unroll
    for (int c = 0; c < 4; ++c) {
      At[(lq * 4 + c) * 68 + lm] = xa[c];
      Bt[(lq * 4 + c) * 68 + lm] = wb[c];
    }
    __syncthreads();
#pragma unroll
    for (int kk = 0; kk < 16; ++kk) {
      vf4 a4 = *(const vf4*)&At[kk * 68 + mm4];
      vf4 b4 = *(const vf4*)&Bt[kk * 68 + nn4];
#pragma unroll
      for (int i = 0; i < 4; ++i)
#pragma unroll
        for (int j = 0; j < 4; ++j) acc[i][j] += a4[i] * b4[j];
    }
  }
#pragma unroll
  for (int i = 0; i < 4; ++i) {
    vf4 o = {fexp2(acc[i][0] * TWO_LOG2E), fexp2(acc[i][1] * TWO_LOG2E),
             fexp2(acc[i][2] * TWO_LOG2E), fexp2(acc[i][3] * TWO_LOG2E)};
    *(vf4*)&C[(mb + mm4 + i) * 256 + n0 + nn4] = o;
  }
}

// ---------------------------------------------------------------------------
// Kernel 2 (dominant): scores via precomputed exponentials.  Unchanged from
// R3 (validated): Wv through scalar cache, 4-way rational rcp combining.
// score = Swv - 2*acc;  E[b][j][i] = masked ? 1 : exp(score); fused row sums
// via atomicAdd into Rsum. Tile 32i x 32j x h=256, grid 8x8x8 = 512.
__global__ __launch_bounds__(256) void scores_exp_kernel(
    const float* __restrict__ QpH, const float* __restrict__ KpH,
    const float* __restrict__ Wv, const int* __restrict__ valid_lens,
    float* __restrict__ E, float* __restrict__ Rsum) {
  __shared__ alignas(16) float Qs[32 * 32];
  __shared__ alignas(16) float Ks[32 * 32];
  const int t = threadIdx.x;
  const int i0 = blockIdx.x * 32;
  const int j0 = blockIdx.y * 32;
  const int b = blockIdx.z;
  const int ti = t & 15;   // i = i0 + ti (+16)
  const int tj = t >> 4;   // j = j0 + tj (+16)

  float Swv;  // sum_h wv[h]
  {
    vf4 w4 = *(const vf4*)&Wv[(t & 63) * 4];
    float sw = w4[0] + w4[1] + w4[2] + w4[3];
#pragma unroll
    for (int off = 1; off < 64; off <<= 1) sw += __shfl_xor(sw, off, 64);
    Swv = sw;
  }

  const int srow = t >> 3;       // staging row 0..31
  const int scg = t & 7;         // staging col-group 0..7
  const int swcol = ((scg ^ (srow & 7)) << 2);
  const int qxor = ti & 7;
  const int kxor = tj & 7;

  float acc[2][2] = {};
  for (int hc = 0; hc < 8; ++hc) {
    __syncthreads();
    const int qoff = (((b << 8) + i0 + srow) << 8) + hc * 32 + scg * 4;
    const int koff = (((b << 8) + j0 + srow) << 8) + hc * 32 + scg * 4;
    vf4 qv = *(const vf4*)&QpH[qoff];
    vf4 qv2 = *(const vf4*)&QpH[524288 + qoff];
    vf4 kv = *(const vf4*)&KpH[koff];
    vf4 kv2 = *(const vf4*)&KpH[524288 + koff];
    *(vf4*)&Qs[srow * 32 + swcol] = qv * qv2;  // product of half-exps
    *(vf4*)&Ks[srow * 32 + swcol] = kv * kv2;
    __syncthreads();
#pragma unroll
    for (int hh = 0; hh < 8; ++hh) {
      vf4 q0 = *(const vf4*)&Qs[ti * 32 + ((hh ^ qxor) << 2)];
      vf4 q1 = *(const vf4*)&Qs[(ti + 16) * 32 + ((hh ^ qxor) << 2)];
      vf4 k0 = *(const vf4*)&Ks[tj * 32 + ((hh ^ kxor) << 2)];
      vf4 k1 = *(const vf4*)&Ks[(tj + 16) * 32 + ((hh ^ kxor) << 2)];
      const int hb = hc * 32 + hh * 4;
      const float w0 = Wv[hb + 0];  // uniform -> scalar cache, not LDS
      const float w1 = Wv[hb + 1];
      const float w2 = Wv[hb + 2];
      const float w3 = Wv[hb + 3];
      // sum_e w_e / A_e with one rcp: (n01*d23 + n23*d01) / (d01*d23)
      auto term = [&](const vf4& q, const vf4& k, float& a) {
        float A0 = __builtin_fmaf(q[0], k[0], 1.0f);
        float A1 = __builtin_fmaf(q[1], k[1], 1.0f);
        float A2 = __builtin_fmaf(q[2], k[2], 1.0f);
        float A3 = __builtin_fmaf(q[3], k[3], 1.0f);
        float d01 = A0 * A1;
        float d23 = A2 * A3;
        float n01 = __builtin_fmaf(w0, A1, w1 * A0);
        float n23 = __builtin_fmaf(w2, A3, w3 * A2);
        float num = __builtin_fmaf(n01, d23, n23 * d01);
        a = __builtin_fmaf(num, frcp(d01 * d23), a);
      };
      term(q0, k0, acc[0][0]);
      term(q0, k1, acc[0][1]);
      term(q1, k0, acc[1][0]);
      term(q1, k1, acc[1][1]);
    }
  }

  const int len = valid_lens[b];
#pragma unroll
  for (int c = 0; c < 2; ++c) {
    const int j = j0 + tj + 16 * c;
    const bool masked = (j >= len);
    float ev[2];
#pragma unroll
    for (int r = 0; r < 2; ++r) {
      const int i = i0 + ti + 16 * r;
      const float score = Swv - 2.0f * acc[r][c];
      ev[r] = masked ? 1.0f : fexp2(score * LOG2E);
      E[(((b << 8) + j) << 8) + i] = ev[r];
    }
    float s = ev[0] + ev[1];
#pragma unroll
    for (int off = 1; off < 16; off <<= 1) s += __shfl_xor(s, off, 64);
    if (ti == 0) atomicAdd(&Rsum[(b << 8) + j], s);
  }
}

// ---------------------------------------------------------------------------
// Kernel 3: out[b,i,d] = sum_j (E[b,j,i]/Rsum[b,j]) * V[b,j,d].
// v2 (kept from R4, under isolation this round): i micro-tile is consecutive
// {2ti, 2ti+1} so the two A-reads fuse into one b64 (was two strided b32):
// 23.6 -> 18 cy/j per wave. Bank check: b64 at As[j*36+2ti], 16 address
// lanes, banks {2ti,2ti+1} all distinct -> conflict-free.
// Tile 32i x 64d, 256 threads, grid 8x4x8 = 256 blocks.
__global__ __launch_bounds__(256) void out_kernel(
    const float* __restrict__ E, const float* __restrict__ Rsum,
    const float* __restrict__ V, float* __restrict__ out) {
  __shared__ alignas(16) float As[32 * 36];  // [j][i]
  __shared__ alignas(16) float Bs[32 * 68];  // [j][d]
  const int t = threadIdx.x;
  const int i0 = blockIdx.x * 32;
  const int d0 = blockIdx.y * 64;
  const int b = blockIdx.z;
  const int ti = t & 15;   // i-pair: rows 2ti, 2ti+1
  const int td = t >> 4;   // d = d0 + td*4
  const int sr = t >> 3;   // staging row 0..31
  const int sc4 = (t & 7) * 4;

  float acc[2][4] = {};
  for (int jc = 0; jc < 8; ++jc) {
    const int jb = jc * 32;
    __syncthreads();
    const float rj = frcp(Rsum[(b << 8) + jb + sr]);
    {
      vf4 a = *(const vf4*)&E[(((b << 8) + jb + sr) << 8) + i0 + sc4];
      *(vf4*)&As[sr * 36 + sc4] = a * rj;
    }
#pragma unroll
    for (int s = 0; s < 2; ++s) {
      const int col = sc4 + s * 32;
      *(vf4*)&Bs[sr * 68 + col] =
          *(const vf4*)&V[(((b << 8) + jb + sr) << 8) + d0 + col];
    }
    __syncthreads();
#pragma unroll
    for (int j = 0; j < 32; ++j) {
      vf2 a = *(const vf2*)&As[j * 36 + 2 * ti];  // rows 2ti, 2ti+1
      vf4 b4 = *(const vf4*)&Bs[j * 68 + td * 4];
#pragma unroll
      for (int c = 0; c < 4; ++c) {
        acc[0][c] += a[0] * b4[c];
        acc[1][c] += a[1] * b4[c];
      }
    }
  }
#pragma unroll
  for (int r = 0; r < 2; ++r) {
    vf4 o = {acc[r][0], acc[r][1], acc[r][2], acc[r][3]};
    *(vf4*)&out[(((b << 8) + i0 + 2 * ti + r) << 8) + d0 + td * 4] = o;
  }
}

// ---------------------------------------------------------------------------
extern "C" void kernel_launch(void* const* d_in, const int* in_sizes, int n_in,
                              void* d_out, int out_size, void* d_ws, size_t ws_size,
                              hipStream_t stream) {
  const float* queries = (const float*)d_in[0];
  const float* keyes = (const float*)d_in[1];
  const float* values = (const float*)d_in[2];
  const int* valid_lens = (const int*)d_in[3];
  const float* Wq = (const float*)d_in[4];
  const float* Wk = (const float*)d_in[5];
  const float* Wv = (const float*)d_in[6];
  float* out = (float*)d_out;

  float* QpH = (float*)d_ws;       // 2 x 2 MB (k-half exponentials)
  float* KpH = QpH + 2 * 524288;   // 2 x 2 MB
  float* E = KpH + 2 * 524288;     // 2 MB, [b][j][i]
  float* Rsum = E + 524288;        // 8 KB, [b][j]

  proj_kernel<<<dim3(64, 4, 2), 256, 0, stream>>>(queries, keyes, Wq, Wk,
                                                  QpH, KpH, Rsum);
  scores_exp_kernel<<<dim3(8, 8, 8), 256, 0, stream>>>(QpH, KpH, Wv,
                                                       valid_lens, E, Rsum);
  out_kernel<<<dim3(8, 4, 8), 256, 0, stream>>>(E, Rsum, values, out);
}